// Round 1
// baseline (437.390 us; speedup 1.0000x reference)
//
#include <hip/hip_runtime.h>
#include <hip/hip_bf16.h>

// Problem constants (from reference)
#define NH      12
#define HD      64
#define HID     768
#define B_      2
#define D_      16
#define QL      32
#define SL      512
#define SEQ     545          // 1 + 32 + 512 tokens per (b,d)
#define RPB     8225         // rows per batch: 1 + 32 + 16*512
#define TOT_ROWS 16450       // B_ * RPB
#define PAD_ROWS 16512       // 129 * 128 (GEMM tile padded)
#define SCALE_  0.125f       // 1/sqrt(64)

typedef __attribute__((ext_vector_type(8))) short short8;   // 8 bf16 = 4 VGPRs (MFMA frag)
typedef __attribute__((ext_vector_type(4))) short short4v;
typedef __attribute__((ext_vector_type(4))) float float4v;

__device__ __forceinline__ short f2bf(float f) {
    __hip_bfloat16 h = __float2bfloat16(f);
    short s;
    __builtin_memcpy(&s, &h, 2);
    return s;
}

// ---------------------------------------------------------------------------
// Kernel 1: gather cls/query/doc fp32 -> contiguous bf16 X [PAD_ROWS x 768]
// Row layout per batch b (base = b*RPB): 0 = cls, 1..32 = query, 33.. = doc.
// Pad rows (>=TOT_ROWS) zeroed so the GEMM needs no bounds checks.
// ---------------------------------------------------------------------------
__global__ __launch_bounds__(256) void pack_kernel(
    const float* __restrict__ cls, const float* __restrict__ query,
    const float* __restrict__ doc, short* __restrict__ X)
{
    int idx = (blockIdx.x * 256 + threadIdx.x) * 4;   // 768 % 4 == 0, no row straddle
    int row = idx / HID;
    int col = idx - row * HID;
    float4 v = make_float4(0.f, 0.f, 0.f, 0.f);
    if (row < TOT_ROWS) {
        int b = row / RPB;
        int r = row - b * RPB;
        const float* src;
        if (r == 0)        src = cls   + b * HID + col;
        else if (r < 33)   src = query + ((size_t)(b * QL + (r - 1))) * HID + col;
        else               src = doc   + ((size_t)(b * (D_ * SL) + (r - 33))) * HID + col;
        v = *reinterpret_cast<const float4*>(src);
    }
    short4v o;
    o[0] = f2bf(v.x); o[1] = f2bf(v.y); o[2] = f2bf(v.z); o[3] = f2bf(v.w);
    *reinterpret_cast<short4v*>(X + idx) = o;
}

// ---------------------------------------------------------------------------
// Kernel 2: Y_p = X @ W_p^T + b_p for p in {q,k,v}; bf16 MFMA 16x16x32.
// 128x128 tile per block, 4 waves each computing a 64x64 quadrant (4x4 MFMAs).
// LDS row stride 40 bf16 (80B) keeps ds_read_b128 conflicts ~2-way (free).
// Both operands are row-major with K contiguous (X rows, W rows) — the
// verified m89/m92 "B^T input" layout: a/b frags both at row=lane&15,
// k=(lane>>4)*8+j; C/D at col=lane&15, row=(lane>>4)*4+reg.
// ---------------------------------------------------------------------------
__global__ __launch_bounds__(256) void proj_gemm(
    const short* __restrict__ X,
    const float* __restrict__ Wq, const float* __restrict__ bq,
    const float* __restrict__ Wk, const float* __restrict__ bk,
    const float* __restrict__ Wv, const float* __restrict__ bv,
    short* __restrict__ Qb, short* __restrict__ Kb, short* __restrict__ Vb)
{
    const float* W; const float* bias; short* Y;
    if (blockIdx.z == 0)      { W = Wq; bias = bq; Y = Qb; }
    else if (blockIdx.z == 1) { W = Wk; bias = bk; Y = Kb; }
    else                      { W = Wv; bias = bv; Y = Vb; }

    __shared__ short Xs[128 * 40];
    __shared__ short Ws_[128 * 40];

    int tid  = threadIdx.x;
    int lane = tid & 63, wave = tid >> 6;
    int m0 = blockIdx.x * 128, n0 = blockIdx.y * 128;
    int moff = (wave & 1) * 64, noff = (wave >> 1) * 64;
    int lr = lane & 15, lg = lane >> 4, lk = lg * 8;

    float4v acc[4][4];
    for (int mi = 0; mi < 4; ++mi)
        for (int ni = 0; ni < 4; ++ni)
            acc[mi][ni] = (float4v){0.f, 0.f, 0.f, 0.f};

    for (int kt = 0; kt < 24; ++kt) {
        int k0 = kt * 32;
        __syncthreads();
        // stage X tile (bf16, vector copy): 128 rows x 32 k
        for (int g = tid; g < 512; g += 256) {
            int row = g >> 2, c8 = (g & 3) * 8;
            *reinterpret_cast<short8*>(&Xs[row * 40 + c8]) =
                *reinterpret_cast<const short8*>(X + (size_t)(m0 + row) * HID + k0 + c8);
        }
        // stage W tile (fp32 -> bf16)
        for (int g = tid; g < 512; g += 256) {
            int row = g >> 2, c8 = (g & 3) * 8;
            const float* wp = W + (size_t)(n0 + row) * HID + k0 + c8;
            float4 w0 = *reinterpret_cast<const float4*>(wp);
            float4 w1 = *reinterpret_cast<const float4*>(wp + 4);
            short8 o;
            o[0] = f2bf(w0.x); o[1] = f2bf(w0.y); o[2] = f2bf(w0.z); o[3] = f2bf(w0.w);
            o[4] = f2bf(w1.x); o[5] = f2bf(w1.y); o[6] = f2bf(w1.z); o[7] = f2bf(w1.w);
            *reinterpret_cast<short8*>(&Ws_[row * 40 + c8]) = o;
        }
        __syncthreads();

        short8 af[4], bfr[4];
        for (int mi = 0; mi < 4; ++mi)
            af[mi]  = *reinterpret_cast<const short8*>(&Xs[(moff + mi * 16 + lr) * 40 + lk]);
        for (int ni = 0; ni < 4; ++ni)
            bfr[ni] = *reinterpret_cast<const short8*>(&Ws_[(noff + ni * 16 + lr) * 40 + lk]);
        for (int mi = 0; mi < 4; ++mi)
            for (int ni = 0; ni < 4; ++ni)
                acc[mi][ni] = __builtin_amdgcn_mfma_f32_16x16x32_bf16(
                    af[mi], bfr[ni], acc[mi][ni], 0, 0, 0);
    }

    // epilogue: + bias, -> bf16, store (rows are padded, always in bounds)
    for (int ni = 0; ni < 4; ++ni) {
        int gcol = n0 + noff + ni * 16 + lr;
        float bb = bias[gcol];
        for (int mi = 0; mi < 4; ++mi) {
            int grow = m0 + moff + mi * 16 + lg * 4;
            for (int r = 0; r < 4; ++r)
                Y[(size_t)(grow + r) * HID + gcol] = f2bf(acc[mi][ni][r] + bb);
        }
    }
}

// ---------------------------------------------------------------------------
// Kernel 3: flash attention over the 545-token set of each (b,d), per head.
// Internal key/query token order: 0..511 = doc, 512 = cls, 513..544 = query
// (softmax is order-invariant; output store remaps to [cls,query,doc]).
// Block = 4 waves, one 64-row Q tile; K loop over 9 tiles of 64 keys.
// ---------------------------------------------------------------------------
__device__ __forceinline__ int row_of(int b, int d, int t) {
    t = t > 544 ? 544 : t;              // clamp pad tokens to a valid row
    int base = b * RPB;
    if (t < 512)  return base + 33 + d * SL + t;   // doc token
    if (t == 512) return base;                     // cls
    return base + (t - 512);                       // query token t-513 -> row base+1+(t-513)
}

__global__ __launch_bounds__(256) void attn_kernel(
    const short* __restrict__ Qb, const short* __restrict__ Kb,
    const short* __restrict__ Vb,
    const float* __restrict__ qmask, const float* __restrict__ dmask,
    float* __restrict__ out)
{
    __shared__ short Ks[64 * 72];      // K tile  [key][dim], stride 72 (2-way banks)
    __shared__ short Vt[64 * 72];      // V^T tile [dim][key]
    __shared__ short Ps[4][16 * 72];   // per-wave P round-trip, stride 72
    __shared__ float maskv[576];       // per-key additive mask (+ -inf for pads)

    int tid  = threadIdx.x;
    int lane = tid & 63, wave = tid >> 6;
    int qt = blockIdx.x, h = blockIdx.y, bd = blockIdx.z;
    int b = bd >> 4, d = bd & 15;
    int lr = lane & 15, lg = lane >> 4, lk = lg * 8;

    for (int i = tid; i < 576; i += 256) {
        float mv;
        if (i < 512)       mv = dmask[(size_t)(b * D_ + d) * SL + i];
        else if (i == 512) mv = 0.f;
        else if (i < 545)  mv = qmask[b * QL + (i - 513)];
        else               mv = -INFINITY;
        maskv[i] = mv;
    }

    // Q fragments (A operand): m = lane&15 -> token qt*64 + wave*16 + lr
    int qtok = qt * 64 + wave * 16 + lr;
    const short* qp = Qb + (size_t)row_of(b, d, qtok) * HID + h * HD + lk;
    short8 aq0 = *reinterpret_cast<const short8*>(qp);
    short8 aq1 = *reinterpret_cast<const short8*>(qp + 32);

    float m_i[4], l_i[4];
    float4v o[4];
    for (int r = 0; r < 4; ++r) { m_i[r] = -INFINITY; l_i[r] = 0.f; }
    for (int nt = 0; nt < 4; ++nt) o[nt] = (float4v){0.f, 0.f, 0.f, 0.f};

    for (int kt = 0; kt < 9; ++kt) {
        __syncthreads();
        {   // stage K tile + transposed V tile (64 keys x 64 dims)
            int key = tid >> 2, c16 = (tid & 3) * 16;
            int grow = row_of(b, d, kt * 64 + key);
            const short* kp = Kb + (size_t)grow * HID + h * HD + c16;
            short8 k0 = *reinterpret_cast<const short8*>(kp);
            short8 k1 = *reinterpret_cast<const short8*>(kp + 8);
            *reinterpret_cast<short8*>(&Ks[key * 72 + c16])     = k0;
            *reinterpret_cast<short8*>(&Ks[key * 72 + c16 + 8]) = k1;
            const short* vp = Vb + (size_t)grow * HID + h * HD + c16;
            short8 v0 = *reinterpret_cast<const short8*>(vp);
            short8 v1 = *reinterpret_cast<const short8*>(vp + 8);
            for (int j = 0; j < 8; ++j) {
                Vt[(c16 + j) * 72 + key]     = v0[j];
                Vt[(c16 + 8 + j) * 72 + key] = v1[j];
            }
        }
        __syncthreads();

        // S = (Q K^T) * SCALE + mask   (C layout: col=key=lane&15, row=lg*4+r)
        float4v s[4];
        for (int nt = 0; nt < 4; ++nt) {
            short8 bk0 = *reinterpret_cast<const short8*>(&Ks[(nt * 16 + lr) * 72 + lk]);
            short8 bk1 = *reinterpret_cast<const short8*>(&Ks[(nt * 16 + lr) * 72 + 32 + lk]);
            float4v z = (float4v){0.f, 0.f, 0.f, 0.f};
            z = __builtin_amdgcn_mfma_f32_16x16x32_bf16(aq0, bk0, z, 0, 0, 0);
            z = __builtin_amdgcn_mfma_f32_16x16x32_bf16(aq1, bk1, z, 0, 0, 0);
            float mk = maskv[kt * 64 + nt * 16 + lr];
            for (int r = 0; r < 4; ++r) s[nt][r] = z[r] * SCALE_ + mk;
        }

        // online softmax; row state (m,l) is reg-indexed -> stays in VGPRs
        float mnew[4], alpha[4];
        for (int r = 0; r < 4; ++r) {
            float mx = fmaxf(fmaxf(s[0][r], s[1][r]), fmaxf(s[2][r], s[3][r]));
            mx = fmaxf(mx, __shfl_xor(mx, 1));
            mx = fmaxf(mx, __shfl_xor(mx, 2));
            mx = fmaxf(mx, __shfl_xor(mx, 4));
            mx = fmaxf(mx, __shfl_xor(mx, 8));
            mnew[r]  = fmaxf(m_i[r], mx);
            alpha[r] = __expf(m_i[r] - mnew[r]);
            m_i[r]   = mnew[r];
        }
        for (int nt = 0; nt < 4; ++nt)
            for (int r = 0; r < 4; ++r)
                s[nt][r] = __expf(s[nt][r] - mnew[r]);   // pad keys: exp(-inf)=0
        for (int r = 0; r < 4; ++r) {
            float sm = s[0][r] + s[1][r] + s[2][r] + s[3][r];
            sm += __shfl_xor(sm, 1);
            sm += __shfl_xor(sm, 2);
            sm += __shfl_xor(sm, 4);
            sm += __shfl_xor(sm, 8);
            l_i[r] = l_i[r] * alpha[r] + sm;
        }

        // P -> per-wave LDS (C layout in, A layout out); rescale O
        short* pw = Ps[wave];
        for (int nt = 0; nt < 4; ++nt) {
            for (int r = 0; r < 4; ++r)
                pw[(lg * 4 + r) * 72 + nt * 16 + lr] = f2bf(s[nt][r]);
            for (int r = 0; r < 4; ++r) o[nt][r] *= alpha[r];
        }
        short8 ap0 = *reinterpret_cast<const short8*>(&pw[lr * 72 + lk]);
        short8 ap1 = *reinterpret_cast<const short8*>(&pw[lr * 72 + 32 + lk]);
        for (int nt = 0; nt < 4; ++nt) {
            short8 bv0 = *reinterpret_cast<const short8*>(&Vt[(nt * 16 + lr) * 72 + lk]);
            short8 bv1 = *reinterpret_cast<const short8*>(&Vt[(nt * 16 + lr) * 72 + 32 + lk]);
            o[nt] = __builtin_amdgcn_mfma_f32_16x16x32_bf16(ap0, bv0, o[nt], 0, 0, 0);
            o[nt] = __builtin_amdgcn_mfma_f32_16x16x32_bf16(ap1, bv1, o[nt], 0, 0, 0);
        }
    }

    // epilogue: O / l, remap token -> output seq [cls(0), query(1..32), doc(33..544)]
    for (int r = 0; r < 4; ++r) {
        int t = qt * 64 + wave * 16 + lg * 4 + r;
        if (t >= SEQ) continue;
        int seq = (t < 512) ? (33 + t) : (t == 512 ? 0 : t - 512);
        float inv = 1.f / l_i[r];
        float* op = out + ((size_t)(bd * SEQ + seq)) * HID + h * HD + lr;
        for (int nt = 0; nt < 4; ++nt)
            op[nt * 16] = o[nt][r] * inv;
    }
}

// ---------------------------------------------------------------------------
// Workspace layout (bf16 elements):
//   X  [PAD_ROWS*768]  @ 0
//   Qb [PAD_ROWS*768]  @ 25.4MB
//   Kb [PAD_ROWS*768]  @ 50.7MB
//   Vb [PAD_ROWS*768]  @ 76.1MB     total ~101.4MB
// ---------------------------------------------------------------------------
extern "C" void kernel_launch(void* const* d_in, const int* in_sizes, int n_in,
                              void* d_out, int out_size, void* d_ws, size_t ws_size,
                              hipStream_t stream)
{
    const float* cls   = (const float*)d_in[0];
    const float* query = (const float*)d_in[1];
    const float* doc   = (const float*)d_in[2];
    const float* qmask = (const float*)d_in[3];
    const float* dmask = (const float*)d_in[4];
    const float* Wq = (const float*)d_in[5];
    const float* bq = (const float*)d_in[6];
    const float* Wk = (const float*)d_in[7];
    const float* bk = (const float*)d_in[8];
    const float* Wv = (const float*)d_in[9];
    const float* bv = (const float*)d_in[10];
    float* out = (float*)d_out;

    short* X  = (short*)d_ws;
    size_t seg = (size_t)PAD_ROWS * HID;
    short* Qb = X + seg;
    short* Kb = Qb + seg;
    short* Vb = Kb + seg;

    pack_kernel<<<dim3((PAD_ROWS * HID / 4) / 256), 256, 0, stream>>>(cls, query, doc, X);
    proj_gemm<<<dim3(PAD_ROWS / 128, HID / 128, 3), 256, 0, stream>>>(
        X, Wq, bq, Wk, bk, Wv, bv, Qb, Kb, Vb);
    attn_kernel<<<dim3(9, NH, B_ * D_), 256, 0, stream>>>(Qb, Kb, Vb, qmask, dmask, out);
}